// Round 6
// baseline (240.515 us; speedup 1.0000x reference)
//
#include <hip/hip_runtime.h>
#include <hip/hip_bf16.h>

// Problem sizes (fixed by reference setup_inputs):
//   B=16, N_LOG=512, N_PHYS(Q)=2048, E=2048
#define BATCH 16
#define NLOG 512
#define Q 2048
#define NEDGE 2048
#define M_TOT (BATCH * NLOG)   // 8192 GEMM rows
#define K_TOT Q                // 2048
#define N_TOT Q                // 2048

typedef short short8 __attribute__((ext_vector_type(8)));
typedef float f32x4 __attribute__((ext_vector_type(4)));
typedef unsigned short us8 __attribute__((ext_vector_type(8)));

// ---------------------------------------------------------------------------
// K1 (fused): blocks [0,8192) convert P fp32->bf16 (8 elem/thread, 16B
// stores); blocks [8192,12288) build Abt[q][p] = (d_hw[p][q]==1) via 32x32
// LDS transpose. Block 0 also zeroes the edge-final done-counter (workspace
// is re-poisoned to 0xAA before every launch).
__global__ __launch_bounds__(256) void prep(const float* __restrict__ P,
                                            __hip_bfloat16* __restrict__ Pb,
                                            const int* __restrict__ d_hw,
                                            __hip_bfloat16* __restrict__ Abt,
                                            unsigned* __restrict__ counter) {
    int bid = blockIdx.x;
    if (bid == 0 && threadIdx.x == 0) *counter = 0u;
    if (bid < 8192) {
        int i = (bid * 256 + threadIdx.x) * 8;
        float4 v0 = *(const float4*)(P + i);
        float4 v1 = *(const float4*)(P + i + 4);
        __hip_bfloat16 tmp[8];
        tmp[0] = __float2bfloat16(v0.x);
        tmp[1] = __float2bfloat16(v0.y);
        tmp[2] = __float2bfloat16(v0.z);
        tmp[3] = __float2bfloat16(v0.w);
        tmp[4] = __float2bfloat16(v1.x);
        tmp[5] = __float2bfloat16(v1.y);
        tmp[6] = __float2bfloat16(v1.z);
        tmp[7] = __float2bfloat16(v1.w);
        *(short8*)(Pb + i) = *(short8*)tmp;
    } else {
        bid -= 8192;
        __shared__ __hip_bfloat16 tile[32][33];
        int q0 = (bid & 63) * 32;
        int p0 = (bid >> 6) * 32;
        int tx = threadIdx.x & 31;
        int ty = threadIdx.x >> 5;  // 0..7
        for (int s = 0; s < 32; s += 8) {
            int p = p0 + ty + s;
            int v = d_hw[(size_t)p * Q + q0 + tx];
            tile[ty + s][tx] = __float2bfloat16(v == 1 ? 1.0f : 0.0f);
        }
        __syncthreads();
        for (int s = 0; s < 32; s += 8) {
            Abt[(size_t)(q0 + ty + s) * Q + p0 + tx] = tile[tx][ty + s];
        }
    }
}

// ---------------------------------------------------------------------------
// K2: main GEMM  PA[M,N] = P[M,K] * Abt[N,K]^T  (bf16 in, fp32 acc, bf16
// out). 256x128 C-tile / 256-thread block, 2x2 waves, each wave 128x64 as
// an 8x4 grid of 16x16x32 MFMAs (MFMA:ds_read = 32/12). Both operands LDS-
// staged via global_load_lds width-16; XOR chunk-swizzle (verified
// conflict-free R3/R4): physical 16B chunk cp at row r holds logical chunk
// cp ^ ((r>>1)&3).
__global__ __launch_bounds__(256, 2) void gemm_bt(const short* __restrict__ A,
                                                  const short* __restrict__ Bt,
                                                  __hip_bfloat16* __restrict__ C) {
    __shared__ short lds[12288];         // As: 256x32, Bs: 128x32
    short* As = lds;
    short* Bs = lds + 8192;

    const int t = threadIdx.x;
    const int w = t >> 6;                // wave 0..3
    const int wr = w >> 1, wc = w & 1;   // 2x2 wave grid
    const int l = t & 63;
    const int quad = l >> 4;             // 0..3
    const int lane16 = l & 15;

    const int m0 = blockIdx.x * 256;
    const int n0 = blockIdx.y * 128;

    const int s_row = t >> 2;                          // 0..63
    const int s_col = ((t & 3) ^ ((t >> 3) & 3)) * 8;  // swizzled k-offset
    const int a_chunk = (quad ^ ((lane16 >> 1) & 3)) * 8;

    f32x4 acc[8][4] = {};

    for (int k0 = 0; k0 < K_TOT; k0 += 32) {
        #pragma unroll
        for (int c = 0; c < 4; c++) {
            const short* gA = A + (size_t)(m0 + c * 64 + s_row) * K_TOT + k0 + s_col;
            __builtin_amdgcn_global_load_lds(
                (const __attribute__((address_space(1))) void*)gA,
                (__attribute__((address_space(3))) void*)(As + c * 2048 + w * 512),
                16, 0, 0);
        }
        #pragma unroll
        for (int c = 0; c < 2; c++) {
            const short* gB = Bt + (size_t)(n0 + c * 64 + s_row) * K_TOT + k0 + s_col;
            __builtin_amdgcn_global_load_lds(
                (const __attribute__((address_space(1))) void*)gB,
                (__attribute__((address_space(3))) void*)(Bs + c * 2048 + w * 512),
                16, 0, 0);
        }
        __syncthreads();

        short8 af[8], bfr[4];
        #pragma unroll
        for (int j = 0; j < 4; j++)
            bfr[j] = *(const short8*)(Bs + (wc * 64 + j * 16 + lane16) * 32 + a_chunk);
        #pragma unroll
        for (int i = 0; i < 8; i++)
            af[i] = *(const short8*)(As + (wr * 128 + i * 16 + lane16) * 32 + a_chunk);

        #pragma unroll
        for (int i = 0; i < 8; i++)
            #pragma unroll
            for (int j = 0; j < 4; j++)
                acc[i][j] = __builtin_amdgcn_mfma_f32_16x16x32_bf16(
                    af[i], bfr[j], acc[i][j], 0, 0, 0);
        __syncthreads();
    }

    #pragma unroll
    for (int i = 0; i < 8; i++) {
        #pragma unroll
        for (int j = 0; j < 4; j++) {
            #pragma unroll
            for (int r = 0; r < 4; r++) {
                int row = m0 + wr * 128 + i * 16 + quad * 4 + r;
                int col = n0 + wc * 64 + j * 16 + lane16;
                C[(size_t)row * N_TOT + col] = __float2bfloat16(acc[i][j][r]);
            }
        }
    }
}

// ---------------------------------------------------------------------------
// K3: score GEMM  S_b[i,j] = sum_q PA_b[i,q] * P_b[j,q]  per batch.
// M=N=512, K=2048 -> 17.2 GFLOP total. 128x128 tile, 2x2 waves, 4x4 MFMAs
// each, same verified swizzle/staging as gemm_bt. Grid (4,4,16).
__global__ __launch_bounds__(256, 2) void gemm_s(const short* __restrict__ PAb,
                                                 const short* __restrict__ Pb,
                                                 __hip_bfloat16* __restrict__ S) {
    __shared__ short lds[8192];          // As: 128x32, Bs: 128x32
    short* As = lds;
    short* Bs = lds + 4096;

    const int t = threadIdx.x;
    const int w = t >> 6;
    const int wr = w >> 1, wc = w & 1;
    const int l = t & 63;
    const int quad = l >> 4;
    const int lane16 = l & 15;

    const int b = blockIdx.z;
    const int m0 = blockIdx.x * 128;
    const int n0 = blockIdx.y * 128;
    const short* A  = PAb + (size_t)b * NLOG * Q;
    const short* Bt = Pb  + (size_t)b * NLOG * Q;
    __hip_bfloat16* C = S + (size_t)b * NLOG * NLOG;

    const int s_row = t >> 2;
    const int s_col = ((t & 3) ^ ((t >> 3) & 3)) * 8;
    const int a_chunk = (quad ^ ((lane16 >> 1) & 3)) * 8;

    f32x4 acc[4][4] = {};

    for (int k0 = 0; k0 < Q; k0 += 32) {
        #pragma unroll
        for (int c = 0; c < 2; c++) {
            const short* gA = A + (size_t)(m0 + c * 64 + s_row) * Q + k0 + s_col;
            __builtin_amdgcn_global_load_lds(
                (const __attribute__((address_space(1))) void*)gA,
                (__attribute__((address_space(3))) void*)(As + c * 2048 + w * 512),
                16, 0, 0);
            const short* gB = Bt + (size_t)(n0 + c * 64 + s_row) * Q + k0 + s_col;
            __builtin_amdgcn_global_load_lds(
                (const __attribute__((address_space(1))) void*)gB,
                (__attribute__((address_space(3))) void*)(Bs + c * 2048 + w * 512),
                16, 0, 0);
        }
        __syncthreads();

        short8 af[4], bfr[4];
        #pragma unroll
        for (int i = 0; i < 4; i++) {
            af[i]  = *(const short8*)(As + (wr * 64 + i * 16 + lane16) * 32 + a_chunk);
            bfr[i] = *(const short8*)(Bs + (wc * 64 + i * 16 + lane16) * 32 + a_chunk);
        }
        #pragma unroll
        for (int i = 0; i < 4; i++)
            #pragma unroll
            for (int j = 0; j < 4; j++)
                acc[i][j] = __builtin_amdgcn_mfma_f32_16x16x32_bf16(
                    af[i], bfr[j], acc[i][j], 0, 0, 0);
        __syncthreads();
    }

    #pragma unroll
    for (int i = 0; i < 4; i++) {
        #pragma unroll
        for (int j = 0; j < 4; j++) {
            #pragma unroll
            for (int r = 0; r < 4; r++) {
                int row = m0 + wr * 64 + i * 16 + quad * 4 + r;
                int col = n0 + wc * 64 + j * 16 + lane16;
                C[(size_t)row * NLOG + col] = __float2bfloat16(acc[i][j][r]);
            }
        }
    }
}

// ---------------------------------------------------------------------------
// K4 (fused): per-batch edge reduction via scalar S-gather + last-block loss
// finalize. One block per batch (S_b is 0.5 MB, L2-resident). Cross-block
// handoff via device-scope atomics + fences (G16: no XCD coherence assumed).
__global__ __launch_bounds__(256) void edge_final(const __hip_bfloat16* __restrict__ S,
                                                  const int* __restrict__ esrc,
                                                  const int* __restrict__ edst,
                                                  const float* __restrict__ ew,
                                                  float* __restrict__ adj,
                                                  float* __restrict__ wsum,
                                                  unsigned* __restrict__ counter,
                                                  float* __restrict__ out) {
    const int b = blockIdx.x;
    const int t = threadIdx.x;
    const unsigned short* Sb = (const unsigned short*)S + (size_t)b * NLOG * NLOG;
    float a = 0.f, ws = 0.f;
    #pragma unroll
    for (int k = 0; k < NEDGE / 256; k++) {
        int e = b * NEDGE + k * 256 + t;
        int src = esrc[e];
        int dst = edst[e];
        float wg = ew[e];
        float s = __uint_as_float((unsigned)Sb[src * NLOG + dst] << 16);
        a += wg * s;
        ws += wg;
    }
    #pragma unroll
    for (int off = 32; off > 0; off >>= 1) {
        a += __shfl_xor(a, off);
        ws += __shfl_xor(ws, off);
    }
    __shared__ float ra[4], rw[4];
    if ((t & 63) == 0) { ra[t >> 6] = a; rw[t >> 6] = ws; }
    __syncthreads();

    __shared__ unsigned done;
    if (t == 0) {
        // device-scope publish of this batch's partials
        atomicExch(&adj[b],  ra[0] + ra[1] + ra[2] + ra[3]);
        atomicExch(&wsum[b], rw[0] + rw[1] + rw[2] + rw[3]);
        __threadfence();
        done = atomicAdd(counter, 1u);
    }
    __syncthreads();
    if (done == BATCH - 1 && t == 0) {
        __threadfence();
        float s = 0.f;
        #pragma unroll
        for (int bb = 0; bb < BATCH; bb++) {
            float av = atomicAdd(&adj[bb], 0.0f);   // device-scope read
            float wv = atomicAdd(&wsum[bb], 0.0f);
            s += av / fmaxf(wv, 1e-8f);
        }
        out[0] = -s / (float)BATCH;
    }
}

// ---------------------------------------------------------------------------
extern "C" void kernel_launch(void* const* d_in, const int* in_sizes, int n_in,
                              void* d_out, int out_size, void* d_ws, size_t ws_size,
                              hipStream_t stream) {
    const float* P    = (const float*)d_in[0];
    const int* d_hw   = (const int*)d_in[1];
    const int* esrc   = (const int*)d_in[2];
    const int* edst   = (const int*)d_in[3];
    const float* ew   = (const float*)d_in[4];
    float* out        = (float*)d_out;

    char* ws = (char*)d_ws;
    // workspace layout (bytes):
    //   Pb   : bf16 [B*N*Q]   = 33,554,432   [0, 33.5M)
    //   Abt  : bf16 [Q*Q]     =  8,388,608   [33.5M, 41.9M)  -- dead after gemm_bt
    //   S    : bf16 [B*N*N]   =  8,388,608   ALIASES Abt slot (exact fit)
    //   PAb  : bf16 [B*N*Q]   = 33,554,432   [41.9M, 75.5M)
    //   adj  : f32 [16]                       (75,497,472)
    //   wsum : f32 [16]                       (75,497,536)
    //   cnt  : u32 [1]                        (75,497,600)
    __hip_bfloat16* Pb  = (__hip_bfloat16*)ws;
    __hip_bfloat16* Abt = (__hip_bfloat16*)(ws + 33554432);
    __hip_bfloat16* S   = (__hip_bfloat16*)(ws + 33554432);  // reuse Abt slot
    __hip_bfloat16* PAb = (__hip_bfloat16*)(ws + 41943040);
    float* adj          = (float*)(ws + 75497472);
    float* wsum         = (float*)(ws + 75497536);
    unsigned* counter   = (unsigned*)(ws + 75497600);

    prep<<<8192 + 4096, 256, 0, stream>>>(P, Pb, d_hw, Abt, counter);
    gemm_bt<<<dim3(M_TOT / 256, N_TOT / 128), 256, 0, stream>>>(
        (const short*)Pb, (const short*)Abt, PAb);
    gemm_s<<<dim3(NLOG / 128, NLOG / 128, BATCH), 256, 0, stream>>>(
        (const short*)PAb, (const short*)Pb, S);
    edge_final<<<BATCH, 256, 0, stream>>>(S, esrc, edst, ew, adj, wsum, counter, out);
}

// Round 7
// 181.446 us; speedup vs baseline: 1.3255x; 1.3255x over previous
//
#include <hip/hip_runtime.h>
#include <hip/hip_bf16.h>

// Problem sizes (fixed by reference setup_inputs):
//   B=16, N_LOG=512, N_PHYS(Q)=2048, E=2048
#define BATCH 16
#define NLOG 512
#define Q 2048
#define NEDGE 2048
#define M_TOT (BATCH * NLOG)   // 8192 GEMM rows
#define KB 2048                // K bytes per row (fp8, 1 B/elem)

typedef float f32x4 __attribute__((ext_vector_type(4)));
typedef int i32x4 __attribute__((ext_vector_type(4)));
typedef int i32x8 __attribute__((ext_vector_type(8)));

// float -> OCP e4m3 byte via HW packed-convert (RNE).
__device__ __forceinline__ unsigned char to_e4m3(float f) {
    int pk = __builtin_amdgcn_cvt_pk_fp8_f32(f, f, 0, false);
    return (unsigned char)(pk & 0xff);
}

// ---------------------------------------------------------------------------
// K1 (fused prep): blocks [0,8192) convert P fp32 -> P8 (e4m3, 8 elem/thr,
// 8B packed stores); blocks [8192,12288) build A8t[q][p] = (d_hw[p][q]==1)
// as e4m3 bytes (1.0 = 0x38) via 32x32 LDS transpose. Block 0 zeroes the
// edge-final done counter.
__global__ __launch_bounds__(256) void prep(const float* __restrict__ P,
                                            unsigned char* __restrict__ P8,
                                            const int* __restrict__ d_hw,
                                            unsigned char* __restrict__ A8t,
                                            unsigned* __restrict__ counter) {
    int bid = blockIdx.x;
    if (bid == 0 && threadIdx.x == 0) *counter = 0u;
    if (bid < 8192) {
        int i = (bid * 256 + threadIdx.x) * 8;
        float4 v0 = *(const float4*)(P + i);
        float4 v1 = *(const float4*)(P + i + 4);
        int lo = 0, hi = 0;
        lo = __builtin_amdgcn_cvt_pk_fp8_f32(v0.x, v0.y, lo, false);
        lo = __builtin_amdgcn_cvt_pk_fp8_f32(v0.z, v0.w, lo, true);
        hi = __builtin_amdgcn_cvt_pk_fp8_f32(v1.x, v1.y, hi, false);
        hi = __builtin_amdgcn_cvt_pk_fp8_f32(v1.z, v1.w, hi, true);
        int2 st; st.x = lo; st.y = hi;
        *(int2*)(P8 + i) = st;
    } else {
        bid -= 8192;
        __shared__ unsigned char tile[32][33];
        int q0 = (bid & 63) * 32;
        int p0 = (bid >> 6) * 32;
        int tx = threadIdx.x & 31;
        int ty = threadIdx.x >> 5;  // 0..7
        for (int s = 0; s < 32; s += 8) {
            int p = p0 + ty + s;
            int v = d_hw[(size_t)p * Q + q0 + tx];
            tile[ty + s][tx] = (v == 1) ? 0x38 : 0x00;  // e4m3 1.0 / 0.0
        }
        __syncthreads();
        for (int s = 0; s < 32; s += 8) {
            A8t[(size_t)(q0 + ty + s) * Q + p0 + tx] = tile[tx][ty + s];
        }
    }
}

// ---------------------------------------------------------------------------
// K2: main GEMM  PA[M,N] = P8[M,K] * A8t[N,K]^T  in fp8-e4m3 via
// mfma_scale_f32_16x16x128_f8f6f4 (unit E8M0 scales = 127). 256x128 C-tile,
// 2x2 waves, wave = 8x4 MFMAs, BK=128 B, 16 K-iters. LDS rows are 128 B =
// exactly 32 banks, so chunk swizzle is phys = logical ^ (row&7): every
// 8-lane phase of a ds_read_b128 covers all 32 banks once. Output written
// as e4m3 of PA/256 (values ~[0.8,1.2]); un-scaled at the edge gather.
__global__ __launch_bounds__(256, 2) void gemm_bt8(const unsigned char* __restrict__ A,
                                                   const unsigned char* __restrict__ Bt,
                                                   unsigned char* __restrict__ PA8) {
    __shared__ unsigned char As[32768];  // 256 x 128
    __shared__ unsigned char Bs[16384];  // 128 x 128

    const int t = threadIdx.x;
    const int w = t >> 6;
    const int wr = w >> 1, wc = w & 1;
    const int l = t & 63;
    const int quad = l >> 4;
    const int lane16 = l & 15;

    const int m0 = blockIdx.x * 256;
    const int n0 = blockIdx.y * 128;

    // staging: each call covers 32 rows x 128 B; thread t -> row t>>3,
    // physical chunk t&7; source logical chunk = (t&7) ^ (row&7).
    const int s_row = t >> 3;                            // 0..31
    const int s_off = (((t & 7) ^ (s_row & 7)) << 4);    // swizzled src byte

    // fragment reads: logical chunks 2q, 2q+1 at row r live at physical
    // chunks (2q)^(r&7), (2q+1)^(r&7).
    const int r7 = lane16 & 7;
    const int c0 = ((2 * quad) ^ r7) << 4;
    const int c1 = ((2 * quad + 1) ^ r7) << 4;

    f32x4 acc[8][4] = {};

    for (int k0 = 0; k0 < KB; k0 += 128) {
        #pragma unroll
        for (int c = 0; c < 8; c++) {
            const unsigned char* g = A + (size_t)(m0 + c * 32 + s_row) * KB + k0 + s_off;
            __builtin_amdgcn_global_load_lds(
                (const __attribute__((address_space(1))) void*)g,
                (__attribute__((address_space(3))) void*)(As + c * 4096 + w * 1024),
                16, 0, 0);
        }
        #pragma unroll
        for (int c = 0; c < 4; c++) {
            const unsigned char* g = Bt + (size_t)(n0 + c * 32 + s_row) * KB + k0 + s_off;
            __builtin_amdgcn_global_load_lds(
                (const __attribute__((address_space(1))) void*)g,
                (__attribute__((address_space(3))) void*)(Bs + c * 4096 + w * 1024),
                16, 0, 0);
        }
        __syncthreads();

        i32x8 bfr[4];
        #pragma unroll
        for (int j = 0; j < 4; j++) {
            int base = (wc * 64 + j * 16 + lane16) << 7;
            i32x4 lo = *(const i32x4*)(Bs + base + c0);
            i32x4 hi = *(const i32x4*)(Bs + base + c1);
            bfr[j] = __builtin_shufflevector(lo, hi, 0, 1, 2, 3, 4, 5, 6, 7);
        }
        #pragma unroll
        for (int i = 0; i < 8; i++) {
            int base = (wr * 128 + i * 16 + lane16) << 7;
            i32x4 lo = *(const i32x4*)(As + base + c0);
            i32x4 hi = *(const i32x4*)(As + base + c1);
            i32x8 af = __builtin_shufflevector(lo, hi, 0, 1, 2, 3, 4, 5, 6, 7);
            #pragma unroll
            for (int j = 0; j < 4; j++)
                acc[i][j] = __builtin_amdgcn_mfma_scale_f32_16x16x128_f8f6f4(
                    af, bfr[j], acc[i][j], 0, 0,   // fmtA=fp8, fmtB=fp8
                    0, 127,                         // opsel_a, scale_a = 2^0
                    0, 127);                        // opsel_b, scale_b = 2^0
        }
        __syncthreads();
    }

    // epilogue: C/D layout (shape-determined): col=lane&15, row=quad*4+reg.
    #pragma unroll
    for (int i = 0; i < 8; i++) {
        #pragma unroll
        for (int j = 0; j < 4; j++) {
            #pragma unroll
            for (int r = 0; r < 4; r++) {
                int row = m0 + wr * 128 + i * 16 + quad * 4 + r;
                int col = n0 + wc * 64 + j * 16 + lane16;
                PA8[(size_t)row * Q + col] = to_e4m3(acc[i][j][r] * (1.0f / 256.0f));
            }
        }
    }
}

// ---------------------------------------------------------------------------
// K3: score GEMM  S_b[i,j] = sum_q PA8_b[i,q] * P8_b[j,q]  per batch, fp8.
// 64x128 tile (grid 8x4x16 = 512 blocks, 2/CU for latency overlap), 2x2
// waves, wave = 2x4 MFMAs. S stored bf16 at 1/256 scale.
__global__ __launch_bounds__(256, 2) void gemm_s8(const unsigned char* __restrict__ PA8,
                                                  const unsigned char* __restrict__ P8,
                                                  __hip_bfloat16* __restrict__ S) {
    __shared__ unsigned char As[8192];   // 64 x 128
    __shared__ unsigned char Bs[16384];  // 128 x 128

    const int t = threadIdx.x;
    const int w = t >> 6;
    const int wr = w >> 1, wc = w & 1;
    const int l = t & 63;
    const int quad = l >> 4;
    const int lane16 = l & 15;

    const int b = blockIdx.z;
    const int m0 = blockIdx.x * 64;
    const int n0 = blockIdx.y * 128;
    const unsigned char* A  = PA8 + (size_t)b * NLOG * Q;
    const unsigned char* Bt = P8  + (size_t)b * NLOG * Q;
    __hip_bfloat16* C = S + (size_t)b * NLOG * NLOG;

    const int s_row = t >> 3;
    const int s_off = (((t & 7) ^ (s_row & 7)) << 4);
    const int r7 = lane16 & 7;
    const int c0 = ((2 * quad) ^ r7) << 4;
    const int c1 = ((2 * quad + 1) ^ r7) << 4;

    f32x4 acc[2][4] = {};

    for (int k0 = 0; k0 < KB; k0 += 128) {
        #pragma unroll
        for (int c = 0; c < 2; c++) {
            const unsigned char* g = A + (size_t)(m0 + c * 32 + s_row) * KB + k0 + s_off;
            __builtin_amdgcn_global_load_lds(
                (const __attribute__((address_space(1))) void*)g,
                (__attribute__((address_space(3))) void*)(As + c * 4096 + w * 1024),
                16, 0, 0);
        }
        #pragma unroll
        for (int c = 0; c < 4; c++) {
            const unsigned char* g = Bt + (size_t)(n0 + c * 32 + s_row) * KB + k0 + s_off;
            __builtin_amdgcn_global_load_lds(
                (const __attribute__((address_space(1))) void*)g,
                (__attribute__((address_space(3))) void*)(Bs + c * 4096 + w * 1024),
                16, 0, 0);
        }
        __syncthreads();

        i32x8 bfr[4];
        #pragma unroll
        for (int j = 0; j < 4; j++) {
            int base = (wc * 64 + j * 16 + lane16) << 7;
            i32x4 lo = *(const i32x4*)(Bs + base + c0);
            i32x4 hi = *(const i32x4*)(Bs + base + c1);
            bfr[j] = __builtin_shufflevector(lo, hi, 0, 1, 2, 3, 4, 5, 6, 7);
        }
        #pragma unroll
        for (int i = 0; i < 2; i++) {
            int base = (wr * 32 + i * 16 + lane16) << 7;
            i32x4 lo = *(const i32x4*)(As + base + c0);
            i32x4 hi = *(const i32x4*)(As + base + c1);
            i32x8 af = __builtin_shufflevector(lo, hi, 0, 1, 2, 3, 4, 5, 6, 7);
            #pragma unroll
            for (int j = 0; j < 4; j++)
                acc[i][j] = __builtin_amdgcn_mfma_scale_f32_16x16x128_f8f6f4(
                    af, bfr[j], acc[i][j], 0, 0, 0, 127, 0, 127);
        }
        __syncthreads();
    }

    #pragma unroll
    for (int i = 0; i < 2; i++) {
        #pragma unroll
        for (int j = 0; j < 4; j++) {
            #pragma unroll
            for (int r = 0; r < 4; r++) {
                int row = m0 + wr * 32 + i * 16 + quad * 4 + r;
                int col = n0 + wc * 64 + j * 16 + lane16;
                C[(size_t)row * NLOG + col] = __float2bfloat16(acc[i][j][r]);
            }
        }
    }
}

// ---------------------------------------------------------------------------
// K4 (fused): per-batch edge reduction via scalar S-gather (x256 to undo the
// PA8 scale) + last-block loss finalize. Device-scope atomics + fences (G16).
__global__ __launch_bounds__(256) void edge_final(const __hip_bfloat16* __restrict__ S,
                                                  const int* __restrict__ esrc,
                                                  const int* __restrict__ edst,
                                                  const float* __restrict__ ew,
                                                  float* __restrict__ adj,
                                                  float* __restrict__ wsum,
                                                  unsigned* __restrict__ counter,
                                                  float* __restrict__ out) {
    const int b = blockIdx.x;
    const int t = threadIdx.x;
    const unsigned short* Sb = (const unsigned short*)S + (size_t)b * NLOG * NLOG;
    float a = 0.f, ws = 0.f;
    #pragma unroll
    for (int k = 0; k < NEDGE / 256; k++) {
        int e = b * NEDGE + k * 256 + t;
        int src = esrc[e];
        int dst = edst[e];
        float wg = ew[e];
        float s = __uint_as_float((unsigned)Sb[src * NLOG + dst] << 16) * 256.0f;
        a += wg * s;
        ws += wg;
    }
    #pragma unroll
    for (int off = 32; off > 0; off >>= 1) {
        a += __shfl_xor(a, off);
        ws += __shfl_xor(ws, off);
    }
    __shared__ float ra[4], rw[4];
    if ((t & 63) == 0) { ra[t >> 6] = a; rw[t >> 6] = ws; }
    __syncthreads();

    __shared__ unsigned done;
    if (t == 0) {
        atomicExch(&adj[b],  ra[0] + ra[1] + ra[2] + ra[3]);
        atomicExch(&wsum[b], rw[0] + rw[1] + rw[2] + rw[3]);
        __threadfence();
        done = atomicAdd(counter, 1u);
    }
    __syncthreads();
    if (done == BATCH - 1 && t == 0) {
        __threadfence();
        float s = 0.f;
        #pragma unroll
        for (int bb = 0; bb < BATCH; bb++) {
            float av = atomicAdd(&adj[bb], 0.0f);   // device-scope read
            float wv = atomicAdd(&wsum[bb], 0.0f);
            s += av / fmaxf(wv, 1e-8f);
        }
        out[0] = -s / (float)BATCH;
    }
}

// ---------------------------------------------------------------------------
extern "C" void kernel_launch(void* const* d_in, const int* in_sizes, int n_in,
                              void* d_out, int out_size, void* d_ws, size_t ws_size,
                              hipStream_t stream) {
    const float* P    = (const float*)d_in[0];
    const int* d_hw   = (const int*)d_in[1];
    const int* esrc   = (const int*)d_in[2];
    const int* edst   = (const int*)d_in[3];
    const float* ew   = (const float*)d_in[4];
    float* out        = (float*)d_out;

    char* ws = (char*)d_ws;
    // workspace layout (bytes), total ~46.2 MB:
    //   P8  : e4m3 [B*N*Q]  = 16,777,216   [0, 16.8M)
    //   A8t : e4m3 [Q*Q]    =  4,194,304   [16.8M, 21.0M)
    //   PA8 : e4m3 [B*N*Q]  = 16,777,216   [21.0M, 37.7M)   (PA/256)
    //   S   : bf16 [B*N*N]  =  8,388,608   [37.7M, 46.1M)   (S/256)
    //   adj/wsum/counter at 46.1M
    unsigned char* P8  = (unsigned char*)ws;
    unsigned char* A8t = (unsigned char*)(ws + 16777216);
    unsigned char* PA8 = (unsigned char*)(ws + 20971520);
    __hip_bfloat16* S  = (__hip_bfloat16*)(ws + 37748736);
    float* adj         = (float*)(ws + 46137344);
    float* wsum        = (float*)(ws + 46137344 + 64);
    unsigned* counter  = (unsigned*)(ws + 46137344 + 128);

    prep<<<8192 + 4096, 256, 0, stream>>>(P, P8, d_hw, A8t, counter);
    gemm_bt8<<<dim3(M_TOT / 256, Q / 128), 256, 0, stream>>>(P8, A8t, PA8);
    gemm_s8<<<dim3(NLOG / 64, NLOG / 128, BATCH), 256, 0, stream>>>(PA8, P8, S);
    edge_final<<<BATCH, 256, 0, stream>>>(S, esrc, edst, ew, adj, wsum, counter, out);
}